// Round 6
// baseline (40.871 us; speedup 1.0000x reference)
//
#include <hip/hip_runtime.h>
#include <math.h>

#define G 24
#define NPTS (G * G)      // 576
#define ROWS (NPTS + 1)   // 577
#define HD 64
#define BH (8 * 12)       // 96
#define EPSF 0.1f
#define COEFF 576.0f
#define BSHIFT 6.3543700408f  // log(575)
#define RPB 16                // rows per block
#define BPI ((ROWS + RPB - 1) / RPB)  // 37 blocks per image

typedef float f32x4 __attribute__((ext_vector_type(4)));

__global__ __launch_bounds__(256) void gaussian_augment_kernel(
    const float* __restrict__ q,
    const float* __restrict__ Wv,
    const float* __restrict__ bv,
    const float* __restrict__ Wa,
    const float* __restrict__ ba,
    float* __restrict__ out)
{
    const int bh  = blockIdx.x / BPI;
    const int blk = blockIdx.x - bh * BPI;
    const int r0  = blk * RPB;
    const int Ract = min(RPB, ROWS - r0);
    const int tid = threadIdx.x;

    __shared__ float s_part[RPB][16][3];        // dot-product partials
    __shared__ float s_par[RPB][4];             // inv0, inv1, alpha
    // s_tab[r][0][k] = alpha*exp(-.5*(in-k)^2*inv0), k=0..24 (24 = dummy pad)
    // s_tab[r][1][k] = exp(-.5*(jn-k)^2*inv1),       k=0..23
    __shared__ float s_tab[RPB][2][32];

    // ---- Phase 1: vectorized partial dot products (NO shuffles) ----
    {
        const int r  = tid >> 4;   // 0..15
        const int kk = tid & 15;   // 0..15 -> k = 4*kk..4*kk+3
        float p0 = 0.f, p1 = 0.f, p2 = 0.f;
        if (r < Ract) {
            const float* qp = q + ((size_t)bh * ROWS + r0 + r) * HD + 4 * kk;
            const f32x4 qv = *(const f32x4*)qp;
            const f32x4 wv0 = *(const f32x4*)(Wv + 8 * kk);      // Wv[2k],Wv[2k+1] pairs
            const f32x4 wv1 = *(const f32x4*)(Wv + 8 * kk + 4);
            const f32x4 wav = *(const f32x4*)(Wa + 4 * kk);
            p0 = qv[0]*wv0[0] + qv[1]*wv0[2] + qv[2]*wv1[0] + qv[3]*wv1[2];
            p1 = qv[0]*wv0[1] + qv[1]*wv0[3] + qv[2]*wv1[1] + qv[3]*wv1[3];
            p2 = qv[0]*wav[0] + qv[1]*wav[1] + qv[2]*wav[2] + qv[3]*wav[3];
        }
        s_part[r][kk][0] = p0;
        s_part[r][kk][1] = p1;
        s_part[r][kk][2] = p2;
    }
    __syncthreads();

    // ---- Phase 2: finish sums + transcendentals, one thread per (row,param) ----
    if (tid < 3 * RPB) {
        const int pr = tid / 3;
        const int pp = tid - 3 * pr;
        if (pr < Ract) {
            float x = 0.f;
            #pragma unroll
            for (int k = 0; k < 16; ++k) x += s_part[pr][k][pp];
            float o;
            if (pp == 2) {
                const float xa = x + ba[0];
                float al = fmaxf(xa, 0.f) + log1pf(expf(-fabsf(xa)));
                if (r0 + pr == 0) al = 0.f;   // prefix pad row -> zeros
                o = al;
            } else {
                const float xx = x + bv[pp] - BSHIFT;
                const float var = COEFF / (1.f + expf(-xx));
                o = 1.f / (var + EPSF);
            }
            s_par[pr][pp] = o;
        }
    }
    __syncthreads();

    // ---- Phase 3: build 49 table entries per row ----
    for (int e = tid; e < 49 * Ract; e += 256) {
        const int rr = (unsigned)e / 49u;
        const int k  = e - 49 * rr;
        const int rg = r0 + rr;
        const int n  = (rg > 0) ? rg - 1 : 0;
        const int in_ = (unsigned)n / 24u;
        const int jn_ = n - in_ * 24;
        if (k < 25) {
            const float t = (float)(in_ - k);
            s_tab[rr][0][k] = s_par[rr][2] * expf(-0.5f * t * t * s_par[rr][0]);
        } else {
            const float t = (float)(jn_ - (k - 25));
            s_tab[rr][1][k - 25] = expf(-0.5f * t * t * s_par[rr][1]);
        }
    }
    __syncthreads();

    // ---- Phase 4: stream, ~1.5 LDS reads/element, aligned nt dwordx4 ----
    const size_t base = ((size_t)bh * ROWS + r0) * ROWS;
    const int span  = Ract * ROWS;
    const size_t S0 = base & ~(size_t)3;
    const int   off = (int)(base - S0);
    const int   nch = (span + off + 3) >> 2;

    for (int idx = tid; idx < nch; idx += 256) {
        const int eb = 4 * idx - off;
        const size_t g0 = S0 + (size_t)4 * idx;
        if (eb >= 0 && eb + 4 <= span) {
            float v0, v1, v2, v3;
            const unsigned eu = (unsigned)eb;
            const int rr = (int)(eu / 577u);
            const int c0 = eb - rr * 577;
            if (c0 >= 1 && c0 <= 573) {
                // fast path: same row, no pad column, im changes at most once
                const int m0  = c0 - 1;
                const int im0 = (unsigned)m0 / 24u;
                const int jm0 = m0 - im0 * 24;
                const float ea = s_tab[rr][0][im0];
                const float eb2 = s_tab[rr][0][im0 + 1];
                const float* t1 = s_tab[rr][1];
                {
                    const int j = jm0;     const bool w = j >= 24;
                    v0 = (w ? eb2 : ea) * t1[w ? j - 24 : j];
                }
                {
                    const int j = jm0 + 1; const bool w = j >= 24;
                    v1 = (w ? eb2 : ea) * t1[w ? j - 24 : j];
                }
                {
                    const int j = jm0 + 2; const bool w = j >= 24;
                    v2 = (w ? eb2 : ea) * t1[w ? j - 24 : j];
                }
                {
                    const int j = jm0 + 3; const bool w = j >= 24;
                    v3 = (w ? eb2 : ea) * t1[w ? j - 24 : j];
                }
            } else {
                // slow path: pad column or row straddle (rare)
                float vv[4];
                #pragma unroll
                for (int t = 0; t < 4; ++t) {
                    const int e = eb + t;
                    const unsigned eu2 = (unsigned)e;
                    const int r2 = (int)(eu2 / 577u);
                    const int c  = e - r2 * 577;
                    float val = 0.f;
                    if (c > 0) {
                        const unsigned m = (unsigned)(c - 1);
                        const int im = (int)(m / 24u);
                        const int jm = (int)m - im * 24;
                        val = s_tab[r2][0][im] * s_tab[r2][1][jm];
                    }
                    vv[t] = val;
                }
                v0 = vv[0]; v1 = vv[1]; v2 = vv[2]; v3 = vv[3];
            }
            f32x4 pk = { v0, v1, v2, v3 };
            __builtin_nontemporal_store(pk, (f32x4*)(out + g0));
        } else {
            // block-edge chunk: predicated scalar stores
            #pragma unroll
            for (int t = 0; t < 4; ++t) {
                const int e = eb + t;
                if (e >= 0 && e < span) {
                    const unsigned eu2 = (unsigned)e;
                    const int r2 = (int)(eu2 / 577u);
                    const int c  = e - r2 * 577;
                    float val = 0.f;
                    if (c > 0) {
                        const unsigned m = (unsigned)(c - 1);
                        const int im = (int)(m / 24u);
                        const int jm = (int)m - im * 24;
                        val = s_tab[r2][0][im] * s_tab[r2][1][jm];
                    }
                    out[g0 + t] = val;
                }
            }
        }
    }
}

extern "C" void kernel_launch(void* const* d_in, const int* in_sizes, int n_in,
                              void* d_out, int out_size, void* d_ws, size_t ws_size,
                              hipStream_t stream) {
    const float* q  = (const float*)d_in[0];
    const float* Wv = (const float*)d_in[1];
    const float* bv = (const float*)d_in[2];
    const float* Wa = (const float*)d_in[3];
    const float* ba = (const float*)d_in[4];
    float* out = (float*)d_out;

    const int grid = BH * BPI;  // 96 * 37 = 3552 blocks
    gaussian_augment_kernel<<<grid, 256, 0, stream>>>(q, Wv, bv, Wa, ba, out);
}

// Round 7
// 38.074 us; speedup vs baseline: 1.0735x; 1.0735x over previous
//
#include <hip/hip_runtime.h>
#include <math.h>

#define G 24
#define NPTS (G * G)      // 576
#define ROWS (NPTS + 1)   // 577
#define HD 64
#define BH (8 * 12)       // 96
#define EPSF 0.1f
#define COEFF 576.0f
#define BSHIFT 6.3543700408f  // log(575)
#define RPB 8                 // rows per block
#define BPI ((ROWS + RPB - 1) / RPB)  // 73 blocks per image

typedef float f32x4 __attribute__((ext_vector_type(4)));

__global__ __launch_bounds__(256) void gaussian_augment_kernel(
    const float* __restrict__ q,
    const float* __restrict__ Wv,
    const float* __restrict__ bv,
    const float* __restrict__ Wa,
    const float* __restrict__ ba,
    float* __restrict__ out)
{
    const int bh  = blockIdx.x / BPI;
    const int blk = blockIdx.x - bh * BPI;
    const int r0  = blk * RPB;
    const int Ract = min(RPB, ROWS - r0);
    const int tid = threadIdx.x;

    __shared__ float s_dot[RPB][3];
    __shared__ float s_par[RPB][3];
    // ABSOLUTE-indexed tables: s_ex0[rr][im] = alpha*exp(-.5*(in-im)^2*inv0)
    __shared__ float s_ex0[RPB][G];
    __shared__ float s_ex1[RPB][G];

    // ---- Phase 1: dot products (3 per row) over head_dim=64 ----
    const int wave = tid >> 6;
    const int lane = tid & 63;
    #pragma unroll
    for (int pass = 0; pass < 2; ++pass) {
        const int rr = wave + 4 * pass;
        if (rr < Ract) {
            const int r = r0 + rr;
            const float* qrow = q + ((size_t)bh * ROWS + r) * HD;
            const float qv = qrow[lane];
            float p0 = qv * Wv[2 * lane + 0];
            float p1 = qv * Wv[2 * lane + 1];
            float p2 = qv * Wa[lane];
            #pragma unroll
            for (int off = 32; off >= 1; off >>= 1) {
                p0 += __shfl_xor(p0, off);
                p1 += __shfl_xor(p1, off);
                p2 += __shfl_xor(p2, off);
            }
            if (lane == 0) {
                s_dot[rr][0] = p0;
                s_dot[rr][1] = p1;
                s_dot[rr][2] = p2;
            }
        }
    }
    __syncthreads();

    // ---- Phase 2: row params — transcendentals ONCE per row ----
    if (tid < Ract) {
        const int r = r0 + tid;
        const float x0 = s_dot[tid][0] + bv[0] - BSHIFT;
        const float x1 = s_dot[tid][1] + bv[1] - BSHIFT;
        const float xa = s_dot[tid][2] + ba[0];
        const float var0 = COEFF / (1.0f + expf(-x0));
        const float var1 = COEFF / (1.0f + expf(-x1));
        s_par[tid][0] = 1.0f / (var0 + EPSF);
        s_par[tid][1] = 1.0f / (var1 + EPSF);
        // softplus (overflow-safe); row 0 is the zero-padding prefix row
        const float alpha = fmaxf(xa, 0.0f) + log1pf(expf(-fabsf(xa)));
        s_par[tid][2] = (r == 0) ? 0.0f : alpha;
    }
    __syncthreads();

    // ---- Phase 3: 48-entry ABSOLUTE exp tables per row ----
    for (int e = tid; e < Ract * 48; e += 256) {
        const int rr = e / 48;
        const int k  = e - rr * 48;                 // 0..47
        const int r  = r0 + rr;
        const int n  = (r > 0) ? r - 1 : 0;
        const int in_ = n / G;
        const int jn_ = n - in_ * G;
        if (k < G) {
            const float t = (float)(in_ - k);       // im = k
            s_ex0[rr][k] = s_par[rr][2] * expf(-0.5f * t * t * s_par[rr][0]);
        } else {
            const float t = (float)(jn_ - (k - G)); // jm = k-G
            s_ex1[rr][k - G] = expf(-0.5f * t * t * s_par[rr][1]);
        }
    }
    __syncthreads();

    // ---- Phase 4: direct compute + aligned dwordx4 PLAIN stores (A/B vs nt) ----
    const size_t base = ((size_t)bh * ROWS + r0) * ROWS;  // first owned element
    const int span  = Ract * ROWS;
    const size_t E  = base + span;                        // exclusive end
    const size_t S0 = base & ~(size_t)3;                  // 16B-aligned start
    const int nch   = (int)((E - S0 + 3) >> 2);           // # float4 chunks

    for (int idx = tid; idx < nch; idx += 256) {
        const size_t g0 = S0 + (size_t)4 * idx;
        const int e0 = (int)((long long)g0 - (long long)base);  // may be -3..-1
        float v[4];
        #pragma unroll
        for (int t = 0; t < 4; ++t) {
            const int e = e0 + t;
            float val = 0.0f;
            if (e >= 0 && e < span) {
                const unsigned eu = (unsigned)e;
                const int rr = (int)(eu / 577u);        // magic-mul
                const int c  = e - rr * 577;
                if (c > 0) {
                    const unsigned m = (unsigned)(c - 1);
                    const int im = (int)(m / 24u);      // magic-mul
                    const int jm = (int)m - im * 24;
                    val = s_ex0[rr][im] * s_ex1[rr][jm];
                }
            }
            v[t] = val;
        }
        if (e0 >= 0 && e0 + 4 <= span) {
            f32x4 pk = { v[0], v[1], v[2], v[3] };
            *(f32x4*)(out + g0) = pk;   // plain store — the only change vs R4
        } else {
            #pragma unroll
            for (int t = 0; t < 4; ++t) {
                const int e = e0 + t;
                if (e >= 0 && e < span) out[g0 + t] = v[t];
            }
        }
    }
}

extern "C" void kernel_launch(void* const* d_in, const int* in_sizes, int n_in,
                              void* d_out, int out_size, void* d_ws, size_t ws_size,
                              hipStream_t stream) {
    const float* q  = (const float*)d_in[0];
    const float* Wv = (const float*)d_in[1];
    const float* bv = (const float*)d_in[2];
    const float* Wa = (const float*)d_in[3];
    const float* ba = (const float*)d_in[4];
    float* out = (float*)d_out;

    const int grid = BH * BPI;  // 96 * 73 = 7008 blocks
    gaussian_augment_kernel<<<grid, 256, 0, stream>>>(q, Wv, bv, Wa, ba, out);
}